// Round 4
// baseline (8343.334 us; speedup 1.0000x reference)
//
#include <hip/hip_runtime.h>
#include <math.h>

#define IN_F 256
#define OUT_F 64
#define BK 256          // rows per bucket
#define ST 16384        // edges per scatter tile

// ---------------------------------------------------------------------------
__global__ __launch_bounds__(256) void zero_i_kernel(int* __restrict__ p, int n) {
  int t = blockIdx.x * blockDim.x + threadIdx.x;
  int stride = gridDim.x * blockDim.x;
  for (; t < n; t += stride) p[t] = 0;
}

// ---------------------------------------------------------------------------
// s0 = x @ W  [N,256]x[256,64] fp32. W transposed into LDS (XOR-swizzled
// float4 rows). Wave per row; lane = out col; x row via uniform broadcast.
__global__ __launch_bounds__(256) void gemm_kernel(const float* __restrict__ x,
    const float* __restrict__ W, float* __restrict__ s0, int N) {
  __shared__ float4 Wt4[64 * 64];
  float* Wtf = (float*)Wt4;
  for (int idx = threadIdx.x; idx < 64 * 256; idx += 256) {
    int k = idx >> 6, n = idx & 63;
    Wtf[(n * 64 + ((k >> 2) ^ n)) * 4 + (k & 3)] = W[idx];
  }
  __syncthreads();
  int lane = threadIdx.x & 63;
  int gw = (blockIdx.x * 256 + threadIdx.x) >> 6;
  int nw = (gridDim.x * 256) >> 6;
  const float4* wrow = &Wt4[lane * 64];
  for (int r = gw; r < N; r += nw) {
    int ru = __builtin_amdgcn_readfirstlane(r);
    const float4* xr = (const float4*)(x + (size_t)ru * IN_F);
    float acc = 0.f;
#pragma unroll 8
    for (int k4 = 0; k4 < 64; ++k4) {
      float4 xv = xr[k4];
      float4 wv = wrow[k4 ^ lane];
      acc = fmaf(xv.x, wv.x, acc);
      acc = fmaf(xv.y, wv.y, acc);
      acc = fmaf(xv.z, wv.z, acc);
      acc = fmaf(xv.w, wv.w, acc);
    }
    s0[(size_t)ru * OUT_F + lane] = acc;
  }
}

// ---------------------------------------------------------------------------
// Bucket histogram: LDS per-block hist of row>>8, merged with one global
// atomic per (block,bucket). gridDim.y = 4 operators.
__global__ __launch_bounds__(256) void bucket_hist(const int* __restrict__ r0,
    const int* __restrict__ r1, const int* __restrict__ r2,
    const int* __restrict__ r3, int* __restrict__ gcnt, int E, int NB) {
  int op = blockIdx.y;
  const int* rows = (op == 0) ? r0 : (op == 1) ? r1 : (op == 2) ? r2 : r3;
  gcnt += (size_t)op * NB;
  __shared__ int hist[512];
  for (int t = threadIdx.x; t < NB; t += 256) hist[t] = 0;
  __syncthreads();
  int t = blockIdx.x * 256 + threadIdx.x;
  int stride = gridDim.x * 256;
  for (; t < E; t += stride) atomicAdd(&hist[rows[t] >> 8], 1);
  __syncthreads();
  for (int k = threadIdx.x; k < NB; k += 256) {
    int c = hist[k];
    if (c) atomicAdd(&gcnt[k], c);
  }
}

// Exclusive scan of the NB bucket counts (one block per operator).
// Writes off[] = bucket start, and resets gcnt[] = start (scatter cursor).
__global__ __launch_bounds__(512) void bucket_scan(int* __restrict__ gcnt,
    int* __restrict__ off, int NB) {
  gcnt += (size_t)blockIdx.x * NB;
  off  += (size_t)blockIdx.x * NB;
  __shared__ int sb[512];
  int t = threadIdx.x;
  int v = (t < NB) ? gcnt[t] : 0;
  sb[t] = v;
  __syncthreads();
  for (int s = 1; s < 512; s <<= 1) {
    int u = (t >= s) ? sb[t - s] : 0;
    __syncthreads();
    sb[t] += u;
    __syncthreads();
  }
  if (t < NB) { int ex = sb[t] - v; off[t] = ex; gcnt[t] = ex; }
}

// Bucket scatter with block-level run aggregation: per tile, LDS hist ->
// reserve a contiguous range per bucket -> write runs. Packs
// (col | rowlow<<18, val) so downstream never reads the index arrays.
__global__ __launch_bounds__(256) void bucket_scatter(const int* __restrict__ r0,
    const int* __restrict__ r1, const int* __restrict__ r2,
    const int* __restrict__ r3, const float* __restrict__ v0,
    const float* __restrict__ v1, const float* __restrict__ v2,
    const float* __restrict__ v3, int* __restrict__ gcnt,
    uint2* __restrict__ S, int E, int NB) {
  int op = blockIdx.y;
  const int* rows  = (op == 0) ? r0 : (op == 1) ? r1 : (op == 2) ? r2 : r3;
  const float* val = (op == 0) ? v0 : (op == 1) ? v1 : (op == 2) ? v2 : v3;
  const int* cols = rows + E;
  gcnt += (size_t)op * NB;
  S    += (size_t)op * E;
  __shared__ int hist[512];
  __shared__ int cur[512];
  for (int t = threadIdx.x; t < NB; t += 256) hist[t] = 0;
  __syncthreads();
  int base = blockIdx.x * ST;
  for (int i = 0; i < ST; i += 256) {
    int e = base + i + threadIdx.x;
    if (e < E) atomicAdd(&hist[rows[e] >> 8], 1);
  }
  __syncthreads();
  for (int t = threadIdx.x; t < NB; t += 256) {
    int c = hist[t];
    cur[t] = c ? atomicAdd(&gcnt[t], c) : 0;
  }
  __syncthreads();
  for (int i = 0; i < ST; i += 256) {
    int e = base + i + threadIdx.x;
    if (e < E) {
      int r = rows[e];
      int pos = atomicAdd(&cur[r >> 8], 1);
      S[pos] = make_uint2((unsigned)cols[e] | ((unsigned)(r & (BK - 1)) << 18),
                          __float_as_uint(val[e]));
    }
  }
}

// ---------------------------------------------------------------------------
// Bucket-local SpMM: one block per bucket (256 rows), 64 KB LDS accumulator.
// Waves stream disjoint contiguous chunks of the bucket's edges; edge records
// are wave-uniform broadcast loads; gathers are coalesced 256 B row reads;
// accumulation via ds_add_f32 (lane-stride-1, conflict-free).
__global__ __launch_bounds__(256) void bucket_spmm(const uint2* __restrict__ S,
    const int* __restrict__ off, const float* __restrict__ xin,
    float* __restrict__ out, int N, int NB, long Sstride, int offStride,
    long outStride, int E) {
  int op = blockIdx.y;
  S   += (size_t)op * Sstride;
  off += (size_t)op * offStride;
  out += (size_t)op * outStride;
  int b = blockIdx.x;
  __shared__ float acc[BK * OUT_F];  // 64 KB
  for (int i = threadIdx.x; i < BK * OUT_F; i += 256) acc[i] = 0.f;
  __syncthreads();
  int lane = threadIdx.x & 63;
  int w = threadIdx.x >> 6;
  int s = off[b];
  int e = (b == NB - 1) ? E : off[b + 1];
  int len = e - s;
  int L = (len + 3) >> 2;
  int js = s + w * L;
  int je = js + L; if (je > e) je = e;
  int j = js;
  for (; j + 8 <= je; j += 8) {
    uint2 d0 = S[j+0], d1 = S[j+1], d2 = S[j+2], d3 = S[j+3];
    uint2 d4 = S[j+4], d5 = S[j+5], d6 = S[j+6], d7 = S[j+7];
    float g0 = xin[(size_t)(d0.x & 0x3FFFF) * OUT_F + lane];
    float g1 = xin[(size_t)(d1.x & 0x3FFFF) * OUT_F + lane];
    float g2 = xin[(size_t)(d2.x & 0x3FFFF) * OUT_F + lane];
    float g3 = xin[(size_t)(d3.x & 0x3FFFF) * OUT_F + lane];
    float g4 = xin[(size_t)(d4.x & 0x3FFFF) * OUT_F + lane];
    float g5 = xin[(size_t)(d5.x & 0x3FFFF) * OUT_F + lane];
    float g6 = xin[(size_t)(d6.x & 0x3FFFF) * OUT_F + lane];
    float g7 = xin[(size_t)(d7.x & 0x3FFFF) * OUT_F + lane];
    atomicAdd(&acc[((d0.x >> 18) << 6) + lane], __uint_as_float(d0.y) * g0);
    atomicAdd(&acc[((d1.x >> 18) << 6) + lane], __uint_as_float(d1.y) * g1);
    atomicAdd(&acc[((d2.x >> 18) << 6) + lane], __uint_as_float(d2.y) * g2);
    atomicAdd(&acc[((d3.x >> 18) << 6) + lane], __uint_as_float(d3.y) * g3);
    atomicAdd(&acc[((d4.x >> 18) << 6) + lane], __uint_as_float(d4.y) * g4);
    atomicAdd(&acc[((d5.x >> 18) << 6) + lane], __uint_as_float(d5.y) * g5);
    atomicAdd(&acc[((d6.x >> 18) << 6) + lane], __uint_as_float(d6.y) * g6);
    atomicAdd(&acc[((d7.x >> 18) << 6) + lane], __uint_as_float(d7.y) * g7);
  }
  for (; j < je; ++j) {
    uint2 d = S[j];
    float g = xin[(size_t)(d.x & 0x3FFFF) * OUT_F + lane];
    atomicAdd(&acc[((d.x >> 18) << 6) + lane], __uint_as_float(d.y) * g);
  }
  __syncthreads();
  size_t gbase = (size_t)b * (BK * OUT_F);
  size_t lim = (size_t)N * OUT_F;
  for (int i = threadIdx.x; i < BK * OUT_F; i += 256) {
    size_t g = gbase + i;
    if (g < lim) out[g] = acc[i];
  }
}

// ---------------------------------------------------------------------------
// Fused epilogue: e (raw-reshape dots), softmax, attention store, h_prime.
__global__ __launch_bounds__(256) void fuse_kernel(const float* __restrict__ s0,
    const float* __restrict__ chan, const float* __restrict__ a,
    float* __restrict__ out_h, float* __restrict__ out_att, int N) {
  int lane = threadIdx.x & 63;
  int i = (blockIdx.x * blockDim.x + threadIdx.x) >> 6;
  if (i >= N) return;
  size_t NF = (size_t)N * OUT_F;
  float e[6];
  int half = N >> 1;
  if (i < half) {
    float lo = s0[(size_t)(2 * i) * OUT_F + lane];
    float hi = s0[(size_t)(2 * i + 1) * OUT_F + lane];
#pragma unroll
    for (int ch = 0; ch < 6; ++ch) {
      float p = fmaf(lo, a[ch * 128 + lane], hi * a[ch * 128 + 64 + lane]);
#pragma unroll
      for (int off = 32; off; off >>= 1) p += __shfl_xor(p, off);
      e[ch] = p;
    }
  } else {
    int r = 2 * i - N;
#pragma unroll
    for (int ch = 0; ch < 6; ++ch) {
      float lo = chan[(size_t)ch * NF + (size_t)r * OUT_F + lane];
      float hi = chan[(size_t)ch * NF + (size_t)(r + 1) * OUT_F + lane];
      if (ch >= 3) { lo = fabsf(lo); hi = fabsf(hi); }
      float p = fmaf(lo, a[ch * 128 + lane], hi * a[ch * 128 + 64 + lane]);
#pragma unroll
      for (int off = 32; off; off >>= 1) p += __shfl_xor(p, off);
      e[ch] = p;
    }
  }
  float m = e[0];
#pragma unroll
  for (int ch = 1; ch < 6; ++ch) m = fmaxf(m, e[ch]);
  float s = 0.f;
#pragma unroll
  for (int ch = 0; ch < 6; ++ch) { e[ch] = expf(e[ch] - m); s += e[ch]; }
  float inv = 1.f / s;
#pragma unroll
  for (int ch = 0; ch < 6; ++ch) e[ch] *= inv;

  if (lane < 6) {
    float v = e[0];
    if (lane == 1) v = e[1];
    if (lane == 2) v = e[2];
    if (lane == 3) v = e[3];
    if (lane == 4) v = e[4];
    if (lane == 5) v = e[5];
    out_att[(size_t)i * 6 + lane] = v;
  }

  float hp = 0.f;
#pragma unroll
  for (int p = 0; p < 6; ++p) {
    int idx = p * 64 + lane;
    int c = idx % 6;
    int j = idx / 6;
    float v = chan[(size_t)c * NF + (size_t)i * OUT_F + j];
    v = (c >= 3) ? fabsf(v) : v;
    hp = fmaf(e[p], v, hp);
  }
  out_h[(size_t)i * OUT_F + lane] = hp * (1.f / 6.f);
}

// ---------------------------------------------------------------------------
extern "C" void kernel_launch(void* const* d_in, const int* in_sizes, int n_in,
                              void* d_out, int out_size, void* d_ws, size_t ws_size,
                              hipStream_t stream) {
  const float* x      = (const float*)d_in[0];
  const float* W      = (const float*)d_in[1];
  const float* a      = (const float*)d_in[2];
  const int*   A_idx  = (const int*)d_in[3];
  const float* A_val  = (const float*)d_in[4];
  const int*   P1_idx = (const int*)d_in[5];
  const float* P1_val = (const float*)d_in[6];
  const int*   P2_idx = (const int*)d_in[7];
  const float* P2_val = (const float*)d_in[8];
  const int*   P3_idx = (const int*)d_in[9];
  const float* P3_val = (const float*)d_in[10];

  int N = in_sizes[0] / IN_F;  // 100000
  int E = in_sizes[4];         // 3200000
  int NB = (N + BK - 1) / BK;  // 391

  size_t NF = (size_t)N * OUT_F;
  float* s0   = (float*)d_ws;
  float* chan = s0 + NF;               // 6 contiguous [N,64] channel buffers
  float* hA  = chan + 0 * NF;
  float* hA2 = chan + 1 * NF;
  float* hA3 = chan + 2 * NF;
  float* hs1 = chan + 3 * NF;
  uint2* S   = (uint2*)(chan + 6 * NF);  // 4 ops x E packed edges
  int* cnt   = (int*)(S + (size_t)4 * E);
  int* off   = cnt + 4 * NB;

  float* out_h   = (float*)d_out;
  float* out_att = out_h + NF;

  int ntiles  = (E + ST - 1) / ST;            // 196
  int fblocks = (N * 64 + 255) / 256;

  zero_i_kernel<<<4, 256, 0, stream>>>(cnt, 4 * NB);
  gemm_kernel<<<512, 256, 0, stream>>>(x, W, s0, N);

  bucket_hist<<<dim3(192, 4), 256, 0, stream>>>(A_idx, P1_idx, P2_idx, P3_idx,
      cnt, E, NB);
  bucket_scan<<<4, 512, 0, stream>>>(cnt, off, NB);
  bucket_scatter<<<dim3(ntiles, 4), 256, 0, stream>>>(A_idx, P1_idx, P2_idx,
      P3_idx, A_val, P1_val, P2_val, P3_val, cnt, S, E, NB);

  // A chain: h_A -> h_A2 -> h_A3 (op 0's S/off; sequential dependency)
  bucket_spmm<<<dim3(NB, 1), 256, 0, stream>>>(S, off, s0,  hA,  N, NB, 0, 0, 0, E);
  bucket_spmm<<<dim3(NB, 1), 256, 0, stream>>>(S, off, hA,  hA2, N, NB, 0, 0, 0, E);
  bucket_spmm<<<dim3(NB, 1), 256, 0, stream>>>(S, off, hA2, hA3, N, NB, 0, 0, 0, E);
  // P1..P3 batched (ops 1..3), all read s0
  bucket_spmm<<<dim3(NB, 3), 256, 0, stream>>>(S + E, off + NB, s0, hs1, N, NB,
      (long)E, NB, (long)NF, E);

  fuse_kernel<<<fblocks, 256, 0, stream>>>(s0, chan, a, out_h, out_att, N);
}

// Round 5
// 7765.716 us; speedup vs baseline: 1.0744x; 1.0744x over previous
//
#include <hip/hip_runtime.h>
#include <math.h>

#define IN_F 256
#define OUT_F 64
#define BK 64           // rows per bucket (16 KB LDS accumulator -> 8 blocks/CU)
#define MAXNB 2048      // LDS array bound for hist/scatter
#define ST 16384        // edges per scatter tile

// ---------------------------------------------------------------------------
__global__ __launch_bounds__(256) void zero_i_kernel(int* __restrict__ p, int n) {
  int t = blockIdx.x * blockDim.x + threadIdx.x;
  int stride = gridDim.x * blockDim.x;
  for (; t < n; t += stride) p[t] = 0;
}

// ---------------------------------------------------------------------------
// s0 = x @ W  [N,256]x[256,64] fp32. W transposed into LDS (XOR-swizzled
// float4 rows). Wave per row; lane = out col; x row via uniform broadcast.
__global__ __launch_bounds__(256) void gemm_kernel(const float* __restrict__ x,
    const float* __restrict__ W, float* __restrict__ s0, int N) {
  __shared__ float4 Wt4[64 * 64];
  float* Wtf = (float*)Wt4;
  for (int idx = threadIdx.x; idx < 64 * 256; idx += 256) {
    int k = idx >> 6, n = idx & 63;
    Wtf[(n * 64 + ((k >> 2) ^ n)) * 4 + (k & 3)] = W[idx];
  }
  __syncthreads();
  int lane = threadIdx.x & 63;
  int gw = (blockIdx.x * 256 + threadIdx.x) >> 6;
  int nw = (gridDim.x * 256) >> 6;
  const float4* wrow = &Wt4[lane * 64];
  for (int r = gw; r < N; r += nw) {
    int ru = __builtin_amdgcn_readfirstlane(r);
    const float4* xr = (const float4*)(x + (size_t)ru * IN_F);
    float acc = 0.f;
#pragma unroll 8
    for (int k4 = 0; k4 < 64; ++k4) {
      float4 xv = xr[k4];
      float4 wv = wrow[k4 ^ lane];
      acc = fmaf(xv.x, wv.x, acc);
      acc = fmaf(xv.y, wv.y, acc);
      acc = fmaf(xv.z, wv.z, acc);
      acc = fmaf(xv.w, wv.w, acc);
    }
    s0[(size_t)ru * OUT_F + lane] = acc;
  }
}

// ---------------------------------------------------------------------------
// Bucket histogram: LDS per-block hist of row/BK, merged with one global
// atomic per (block,bucket). gridDim.y = 4 operators.
__global__ __launch_bounds__(256) void bucket_hist(const int* __restrict__ r0,
    const int* __restrict__ r1, const int* __restrict__ r2,
    const int* __restrict__ r3, int* __restrict__ gcnt, int E, int NB) {
  int op = blockIdx.y;
  const int* rows = (op == 0) ? r0 : (op == 1) ? r1 : (op == 2) ? r2 : r3;
  gcnt += (size_t)op * NB;
  __shared__ int hist[MAXNB];
  for (int t = threadIdx.x; t < NB; t += 256) hist[t] = 0;
  __syncthreads();
  int t = blockIdx.x * 256 + threadIdx.x;
  int stride = gridDim.x * 256;
  for (; t < E; t += stride) atomicAdd(&hist[rows[t] >> 6], 1);
  __syncthreads();
  for (int k = threadIdx.x; k < NB; k += 256) {
    int c = hist[k];
    if (c) atomicAdd(&gcnt[k], c);
  }
}

// Exclusive scan of NB bucket counts; one block per operator, chunked with
// carry. Writes off[] = bucket start; resets gcnt[] = start (scatter cursor).
__global__ __launch_bounds__(256) void bucket_scan(int* __restrict__ gcnt,
    int* __restrict__ off, int NB) {
  gcnt += (size_t)blockIdx.x * NB;
  off  += (size_t)blockIdx.x * NB;
  __shared__ int sb[256];
  __shared__ int carry;
  if (threadIdx.x == 0) carry = 0;
  __syncthreads();
  for (int base = 0; base < NB; base += 256) {
    int i = base + threadIdx.x;
    int v = (i < NB) ? gcnt[i] : 0;
    sb[threadIdx.x] = v;
    __syncthreads();
    for (int s = 1; s < 256; s <<= 1) {
      int u = (threadIdx.x >= s) ? sb[threadIdx.x - s] : 0;
      __syncthreads();
      sb[threadIdx.x] += u;
      __syncthreads();
    }
    int ex = carry + sb[threadIdx.x] - v;   // reads old carry
    if (i < NB) { off[i] = ex; gcnt[i] = ex; }
    __syncthreads();
    if (threadIdx.x == 255) carry += sb[255];
    __syncthreads();
  }
}

// Bucket scatter with block-level run aggregation: per tile, LDS hist ->
// reserve a contiguous range per bucket -> write runs. Packs
// (col | rowlow<<18, val): col 18 bits, row-in-bucket 6 bits.
__global__ __launch_bounds__(256) void bucket_scatter(const int* __restrict__ r0,
    const int* __restrict__ r1, const int* __restrict__ r2,
    const int* __restrict__ r3, const float* __restrict__ v0,
    const float* __restrict__ v1, const float* __restrict__ v2,
    const float* __restrict__ v3, int* __restrict__ gcnt,
    uint2* __restrict__ S, int E, int NB) {
  int op = blockIdx.y;
  const int* rows  = (op == 0) ? r0 : (op == 1) ? r1 : (op == 2) ? r2 : r3;
  const float* val = (op == 0) ? v0 : (op == 1) ? v1 : (op == 2) ? v2 : v3;
  const int* cols = rows + E;
  gcnt += (size_t)op * NB;
  S    += (size_t)op * E;
  __shared__ int hist[MAXNB];
  __shared__ int cur[MAXNB];
  for (int t = threadIdx.x; t < NB; t += 256) hist[t] = 0;
  __syncthreads();
  int base = blockIdx.x * ST;
  for (int i = 0; i < ST; i += 256) {
    int e = base + i + threadIdx.x;
    if (e < E) atomicAdd(&hist[rows[e] >> 6], 1);
  }
  __syncthreads();
  for (int t = threadIdx.x; t < NB; t += 256) {
    int c = hist[t];
    cur[t] = c ? atomicAdd(&gcnt[t], c) : 0;
  }
  __syncthreads();
  for (int i = 0; i < ST; i += 256) {
    int e = base + i + threadIdx.x;
    if (e < E) {
      int r = rows[e];
      int pos = atomicAdd(&cur[r >> 6], 1);
      S[pos] = make_uint2((unsigned)cols[e] | ((unsigned)(r & (BK - 1)) << 18),
                          __float_as_uint(val[e]));
    }
  }
}

// ---------------------------------------------------------------------------
// Bucket-local SpMM: one block per 64-row bucket, 16 KB LDS accumulator
// (8 blocks/CU -> full wave occupancy). Waves stream disjoint contiguous
// chunks of the bucket's edges (wave-uniform broadcast loads), gather
// coalesced 256 B rows of xin, accumulate via LDS atomics (stride-1 lanes,
// conflict-free), then one coalesced 16 KB store.
__global__ __launch_bounds__(256) void bucket_spmm(const uint2* __restrict__ S,
    const int* __restrict__ off, const float* __restrict__ xin,
    float* __restrict__ out, int N, int NB, long Sstride, int offStride,
    long outStride, int E) {
  int op = blockIdx.y;
  S   += (size_t)op * Sstride;
  off += (size_t)op * offStride;
  out += (size_t)op * outStride;
  int b = blockIdx.x;
  __shared__ float acc[BK * OUT_F];  // 16 KB
  for (int i = threadIdx.x; i < BK * OUT_F; i += 256) acc[i] = 0.f;
  __syncthreads();
  int lane = threadIdx.x & 63;
  int w = threadIdx.x >> 6;
  int s = off[b];
  int e = (b == NB - 1) ? E : off[b + 1];
  int len = e - s;
  int L = (len + 3) >> 2;
  int js = s + w * L;
  int je = js + L; if (je > e) je = e;
  int j = js;
  for (; j + 8 <= je; j += 8) {
    uint2 d0 = S[j+0], d1 = S[j+1], d2 = S[j+2], d3 = S[j+3];
    uint2 d4 = S[j+4], d5 = S[j+5], d6 = S[j+6], d7 = S[j+7];
    float g0 = xin[(size_t)(d0.x & 0x3FFFF) * OUT_F + lane];
    float g1 = xin[(size_t)(d1.x & 0x3FFFF) * OUT_F + lane];
    float g2 = xin[(size_t)(d2.x & 0x3FFFF) * OUT_F + lane];
    float g3 = xin[(size_t)(d3.x & 0x3FFFF) * OUT_F + lane];
    float g4 = xin[(size_t)(d4.x & 0x3FFFF) * OUT_F + lane];
    float g5 = xin[(size_t)(d5.x & 0x3FFFF) * OUT_F + lane];
    float g6 = xin[(size_t)(d6.x & 0x3FFFF) * OUT_F + lane];
    float g7 = xin[(size_t)(d7.x & 0x3FFFF) * OUT_F + lane];
    atomicAdd(&acc[((d0.x >> 18) << 6) + lane], __uint_as_float(d0.y) * g0);
    atomicAdd(&acc[((d1.x >> 18) << 6) + lane], __uint_as_float(d1.y) * g1);
    atomicAdd(&acc[((d2.x >> 18) << 6) + lane], __uint_as_float(d2.y) * g2);
    atomicAdd(&acc[((d3.x >> 18) << 6) + lane], __uint_as_float(d3.y) * g3);
    atomicAdd(&acc[((d4.x >> 18) << 6) + lane], __uint_as_float(d4.y) * g4);
    atomicAdd(&acc[((d5.x >> 18) << 6) + lane], __uint_as_float(d5.y) * g5);
    atomicAdd(&acc[((d6.x >> 18) << 6) + lane], __uint_as_float(d6.y) * g6);
    atomicAdd(&acc[((d7.x >> 18) << 6) + lane], __uint_as_float(d7.y) * g7);
  }
  for (; j < je; ++j) {
    uint2 d = S[j];
    float g = xin[(size_t)(d.x & 0x3FFFF) * OUT_F + lane];
    atomicAdd(&acc[((d.x >> 18) << 6) + lane], __uint_as_float(d.y) * g);
  }
  __syncthreads();
  size_t gbase = (size_t)b * (BK * OUT_F);
  size_t lim = (size_t)N * OUT_F;
  for (int i = threadIdx.x; i < BK * OUT_F; i += 256) {
    size_t g = gbase + i;
    if (g < lim) out[g] = acc[i];
  }
}

// ---------------------------------------------------------------------------
// Fused epilogue: e (raw-reshape dots), softmax, attention store, h_prime.
__global__ __launch_bounds__(256) void fuse_kernel(const float* __restrict__ s0,
    const float* __restrict__ chan, const float* __restrict__ a,
    float* __restrict__ out_h, float* __restrict__ out_att, int N) {
  int lane = threadIdx.x & 63;
  int i = (blockIdx.x * blockDim.x + threadIdx.x) >> 6;
  if (i >= N) return;
  size_t NF = (size_t)N * OUT_F;
  float e[6];
  int half = N >> 1;
  if (i < half) {
    float lo = s0[(size_t)(2 * i) * OUT_F + lane];
    float hi = s0[(size_t)(2 * i + 1) * OUT_F + lane];
#pragma unroll
    for (int ch = 0; ch < 6; ++ch) {
      float p = fmaf(lo, a[ch * 128 + lane], hi * a[ch * 128 + 64 + lane]);
#pragma unroll
      for (int off = 32; off; off >>= 1) p += __shfl_xor(p, off);
      e[ch] = p;
    }
  } else {
    int r = 2 * i - N;
#pragma unroll
    for (int ch = 0; ch < 6; ++ch) {
      float lo = chan[(size_t)ch * NF + (size_t)r * OUT_F + lane];
      float hi = chan[(size_t)ch * NF + (size_t)(r + 1) * OUT_F + lane];
      if (ch >= 3) { lo = fabsf(lo); hi = fabsf(hi); }
      float p = fmaf(lo, a[ch * 128 + lane], hi * a[ch * 128 + 64 + lane]);
#pragma unroll
      for (int off = 32; off; off >>= 1) p += __shfl_xor(p, off);
      e[ch] = p;
    }
  }
  float m = e[0];
#pragma unroll
  for (int ch = 1; ch < 6; ++ch) m = fmaxf(m, e[ch]);
  float s = 0.f;
#pragma unroll
  for (int ch = 0; ch < 6; ++ch) { e[ch] = expf(e[ch] - m); s += e[ch]; }
  float inv = 1.f / s;
#pragma unroll
  for (int ch = 0; ch < 6; ++ch) e[ch] *= inv;

  if (lane < 6) {
    float v = e[0];
    if (lane == 1) v = e[1];
    if (lane == 2) v = e[2];
    if (lane == 3) v = e[3];
    if (lane == 4) v = e[4];
    if (lane == 5) v = e[5];
    out_att[(size_t)i * 6 + lane] = v;
  }

  float hp = 0.f;
#pragma unroll
  for (int p = 0; p < 6; ++p) {
    int idx = p * 64 + lane;
    int c = idx % 6;
    int j = idx / 6;
    float v = chan[(size_t)c * NF + (size_t)i * OUT_F + j];
    v = (c >= 3) ? fabsf(v) : v;
    hp = fmaf(e[p], v, hp);
  }
  out_h[(size_t)i * OUT_F + lane] = hp * (1.f / 6.f);
}

// ---------------------------------------------------------------------------
extern "C" void kernel_launch(void* const* d_in, const int* in_sizes, int n_in,
                              void* d_out, int out_size, void* d_ws, size_t ws_size,
                              hipStream_t stream) {
  const float* x      = (const float*)d_in[0];
  const float* W      = (const float*)d_in[1];
  const float* a      = (const float*)d_in[2];
  const int*   A_idx  = (const int*)d_in[3];
  const float* A_val  = (const float*)d_in[4];
  const int*   P1_idx = (const int*)d_in[5];
  const float* P1_val = (const float*)d_in[6];
  const int*   P2_idx = (const int*)d_in[7];
  const float* P2_val = (const float*)d_in[8];
  const int*   P3_idx = (const int*)d_in[9];
  const float* P3_val = (const float*)d_in[10];

  int N = in_sizes[0] / IN_F;  // 100000
  int E = in_sizes[4];         // 3200000
  int NB = (N + BK - 1) / BK;  // 1563

  size_t NF = (size_t)N * OUT_F;
  float* s0   = (float*)d_ws;
  float* chan = s0 + NF;               // 6 contiguous [N,64] channel buffers
  float* hA  = chan + 0 * NF;
  float* hA2 = chan + 1 * NF;
  float* hA3 = chan + 2 * NF;
  float* hs1 = chan + 3 * NF;
  uint2* S   = (uint2*)(chan + 6 * NF);  // 4 ops x E packed edges
  int* cnt   = (int*)(S + (size_t)4 * E);
  int* off   = cnt + 4 * NB;

  float* out_h   = (float*)d_out;
  float* out_att = out_h + NF;

  int ntiles  = (E + ST - 1) / ST;            // 196 per op
  int fblocks = (N * 64 + 255) / 256;

  zero_i_kernel<<<8, 256, 0, stream>>>(cnt, 4 * NB);
  gemm_kernel<<<512, 256, 0, stream>>>(x, W, s0, N);

  bucket_hist<<<dim3(192, 4), 256, 0, stream>>>(A_idx, P1_idx, P2_idx, P3_idx,
      cnt, E, NB);
  bucket_scan<<<4, 256, 0, stream>>>(cnt, off, NB);
  bucket_scatter<<<dim3(ntiles, 4), 256, 0, stream>>>(A_idx, P1_idx, P2_idx,
      P3_idx, A_val, P1_val, P2_val, P3_val, cnt, S, E, NB);

  // A chain: h_A -> h_A2 -> h_A3 (op 0's S/off; sequential dependency)
  bucket_spmm<<<dim3(NB, 1), 256, 0, stream>>>(S, off, s0,  hA,  N, NB, 0, 0, 0, E);
  bucket_spmm<<<dim3(NB, 1), 256, 0, stream>>>(S, off, hA,  hA2, N, NB, 0, 0, 0, E);
  bucket_spmm<<<dim3(NB, 1), 256, 0, stream>>>(S, off, hA2, hA3, N, NB, 0, 0, 0, E);
  // P1..P3 batched (ops 1..3), all read s0
  bucket_spmm<<<dim3(NB, 3), 256, 0, stream>>>(S + E, off + NB, s0, hs1, N, NB,
      (long)E, NB, (long)NF, E);

  fuse_kernel<<<fblocks, 256, 0, stream>>>(s0, chan, a, out_h, out_att, N);
}